// Round 10
// baseline (40.806 us; speedup 1.0000x reference)
//
#include <hip/hip_runtime.h>

#define NP 16384
#define NS 8192
#define DP 256
#define DS 128
#define DI 128

// ---- k1 geometry: 4-wave blocks, 16 rows/wave fully unrolled ----
#define NBP 256               // prot blocks: 64 rows each
#define NBS 128               // sub blocks: 64 rows each
#define G1  (NBP + NBS)       // 384
#define BLK1 256

// ---- ws float offsets ----
#define RP_OFF 0                      // [NBP][DS] projected prot partials (-> u_s)
#define RS_OFF (RP_OFF + NBP*DS)      // [NBS][DP] projected sub partials (-> u_p)
#define ZP_OFF (RS_OFF + NBS*DP)      // [NBP]
#define ZS_OFF (ZP_OFF + NBP)         // [NBS]
#define BSC    (ZS_OFF + NBS)         // [DS] bso + Wso^T bpp
#define BPC    (BSC + DS)             // [DP] bpo + Wpo^T bsp

// ---- out float offsets ----
#define O1 (NP*DP)
#define O2 (O1 + NP)
#define O3 (O2 + NS*DS)
#define TOTAL (O3 + NS)
#define TOTAL4 (TOTAL/4)     // 1316864
#define G2  1024
#define CH4 (TOTAL4 / G2)    // 1286 exactly

// ---- k1: fused gather-weight + weighted colsum + per-block projection ----
__global__ __launch_bounds__(BLK1)
void k1(const float* __restrict__ pn, const float* __restrict__ sn,
        const float* __restrict__ Wpp, const float* __restrict__ bpp,
        const float* __restrict__ Wsp, const float* __restrict__ bsp,
        const float* __restrict__ Wpo, const float* __restrict__ bpo,
        const float* __restrict__ Wso, const float* __restrict__ bso,
        const int* __restrict__ pidx, const int* __restrict__ sidx,
        float* __restrict__ ws) {
    __shared__ float wcol[DP];
    __shared__ float racc[4 * DP];
    __shared__ float rz[4];
    __shared__ float acc2[DP];
    __shared__ float qv[DI];
    __shared__ float red[BLK1];
    const int t = threadIdx.x;
    const int lane = t & 63;
    const int wv = t >> 6;
    const int b = blockIdx.x;

    if (b < NBP) {
        // ---- prot side: 64 rows/block, 16 per wave, FULLY UNROLLED ----
        {
            const float4* row = (const float4*)(Wpp + t * DI);
            float s = 0.f;
            #pragma unroll
            for (int d = 0; d < DI / 4; ++d) { float4 v = row[d]; s += v.x + v.y + v.z + v.w; }
            wcol[t] = s;
        }
        __syncthreads();
        const float4 wp = *(const float4*)(wcol + lane * 4);
        float4 acc = make_float4(0.f, 0.f, 0.f, 0.f);
        float z = 0.f;
        const int base = b * 64 + wv * 16;
        #pragma unroll
        for (int k = 0; k < 16; k += 2) {
            const int i0 = base + k, i1 = base + k + 1;
            const int g0 = pidx[i0], g1 = pidx[i1];
            const float4 x0 = *(const float4*)(pn + (size_t)g0 * DP + lane * 4);
            const float4 x1 = *(const float4*)(pn + (size_t)g1 * DP + lane * 4);
            float s0 = x0.x * wp.x + x0.y * wp.y + x0.z * wp.z + x0.w * wp.w;
            float s1 = x1.x * wp.x + x1.y * wp.y + x1.z * wp.z + x1.w * wp.w;
            #pragma unroll
            for (int m = 32; m >= 1; m >>= 1) {
                s0 += __shfl_xor(s0, m, 64);
                s1 += __shfl_xor(s1, m, 64);
            }
            const float e0 = __expf(s0), e1 = __expf(s1);
            const float4 y0 = *(const float4*)(pn + (size_t)i0 * DP + lane * 4);
            const float4 y1 = *(const float4*)(pn + (size_t)i1 * DP + lane * 4);
            acc.x += e0 * y0.x + e1 * y1.x;
            acc.y += e0 * y0.y + e1 * y1.y;
            acc.z += e0 * y0.z + e1 * y1.z;
            acc.w += e0 * y0.w + e1 * y1.w;
            z += e0 + e1;
        }
        ((float4*)(racc + wv * DP))[lane] = acc;
        if (lane == 0) rz[wv] = z;
        __syncthreads();
        acc2[t] = racc[t] + racc[DP + t] + racc[2 * DP + t] + racc[3 * DP + t];
        if (t == 0) ws[ZP_OFF + b] = rz[0] + rz[1] + rz[2] + rz[3];
        __syncthreads();
        // stage A: q[d] = sum_c acc2[c]*Wpp[c][d]  (c<256, d<128)
        {
            const int d = t & 127, g = t >> 7;     // 2 groups of 128 c's
            float a = 0.f;
            #pragma unroll 8
            for (int c = g * 128; c < g * 128 + 128; ++c) a += acc2[c] * Wpp[c * DI + d];
            red[t] = a;
        }
        __syncthreads();
        if (t < DI) qv[t] = red[t] + red[t + 128];
        __syncthreads();
        // stage B: r[c] = sum_d qv[d]*Wso[d][c]  (d<128, c<128)
        {
            const int c = t & 127, g = t >> 7;     // 2 groups of 64 d's
            float a = 0.f;
            #pragma unroll 8
            for (int d = g * 64; d < g * 64 + 64; ++d) a += qv[d] * Wso[d * DS + c];
            red[t] = a;
        }
        __syncthreads();
        if (t < DS) ws[RP_OFF + b * DS + t] = red[t] + red[t + 128];
        if (b == 0) {  // BSC = bso + Wso^T bpp
            __syncthreads();
            {
                const int c = t & 127, g = t >> 7;
                float a = 0.f;
                #pragma unroll 8
                for (int d = g * 64; d < g * 64 + 64; ++d) a += bpp[d] * Wso[d * DS + c];
                red[t] = a;
            }
            __syncthreads();
            if (t < DS) ws[BSC + t] = bso[t] + red[t] + red[t + 128];
        }
    } else {
        // ---- sub side: 64 rows/block, 16 per wave, FULLY UNROLLED ----
        const int b2 = b - NBP;
        if (t < DS) {
            const float4* row = (const float4*)(Wsp + t * DI);
            float s = 0.f;
            #pragma unroll
            for (int d = 0; d < DI / 4; ++d) { float4 v = row[d]; s += v.x + v.y + v.z + v.w; }
            wcol[t] = s;
        }
        __syncthreads();
        const float2 wp = *(const float2*)(wcol + lane * 2);
        float2 acc = make_float2(0.f, 0.f);
        float z = 0.f;
        const int base = b2 * 64 + wv * 16;
        #pragma unroll
        for (int k = 0; k < 16; k += 2) {
            const int j0 = base + k, j1 = base + k + 1;
            const int g0 = sidx[j0], g1 = sidx[j1];
            const float2 x0 = *(const float2*)(sn + (size_t)g0 * DS + lane * 2);
            const float2 x1 = *(const float2*)(sn + (size_t)g1 * DS + lane * 2);
            float s0 = x0.x * wp.x + x0.y * wp.y;
            float s1 = x1.x * wp.x + x1.y * wp.y;
            #pragma unroll
            for (int m = 32; m >= 1; m >>= 1) {
                s0 += __shfl_xor(s0, m, 64);
                s1 += __shfl_xor(s1, m, 64);
            }
            const float e0 = __expf(s0), e1 = __expf(s1);
            const float2 y0 = *(const float2*)(sn + (size_t)j0 * DS + lane * 2);
            const float2 y1 = *(const float2*)(sn + (size_t)j1 * DS + lane * 2);
            acc.x += e0 * y0.x + e1 * y1.x;
            acc.y += e0 * y0.y + e1 * y1.y;
            z += e0 + e1;
        }
        ((float2*)(racc + wv * DS))[lane] = acc;
        if (lane == 0) rz[wv] = z;
        __syncthreads();
        if (t < DS) acc2[t] = racc[t] + racc[DS + t] + racc[2 * DS + t] + racc[3 * DS + t];
        if (t == 0) ws[ZS_OFF + b2] = rz[0] + rz[1] + rz[2] + rz[3];
        __syncthreads();
        // stage A: q[d] = sum_c acc2[c]*Wsp[c][d]  (c<128, d<128)
        {
            const int d = t & 127, g = t >> 7;     // 2 groups of 64 c's
            float a = 0.f;
            #pragma unroll 8
            for (int c = g * 64; c < g * 64 + 64; ++c) a += acc2[c] * Wsp[c * DI + d];
            red[t] = a;
        }
        __syncthreads();
        if (t < DI) qv[t] = red[t] + red[t + 128];
        __syncthreads();
        // stage B: r[c] = sum_d qv[d]*Wpo[d][c]  (d<128, c<256) — one c per thread
        {
            float a = 0.f;
            #pragma unroll 8
            for (int d = 0; d < DI; ++d) a += qv[d] * Wpo[d * DP + t];
            ws[RS_OFF + b2 * DP + t] = a;
        }
        if (b2 == 0) {  // BPC = bpo + Wpo^T bsp
            float a = bpo[t];
            #pragma unroll 8
            for (int d = 0; d < DI; ++d) a += bsp[d] * Wpo[d * DP + t];
            ws[BPC + t] = a;
        }
    }
}

// ---- k2: R6-exact combine-then-stream (partial counts adapted) ----
__global__ __launch_bounds__(512)
void k2(const float* __restrict__ pn, const float* __restrict__ sn,
        const int* __restrict__ pidx, const int* __restrict__ sidx,
        const float* __restrict__ ws, float* __restrict__ out) {
    __shared__ float up[DP];
    __shared__ float us[DS];
    __shared__ float red[512];
    __shared__ float zsh[2];
    const int t = threadIdx.x;
    const int lane = t & 63;
    const int wv = t >> 6;
    const int b = blockIdx.x;
    const int start4 = b * CH4;
    const int end4 = start4 + CH4;

    if (wv == 0) {     // ZP: 256 entries
        float z = ws[ZP_OFF + lane] + ws[ZP_OFF + 64 + lane]
                + ws[ZP_OFF + 128 + lane] + ws[ZP_OFF + 192 + lane];
        #pragma unroll
        for (int m = 32; m >= 1; m >>= 1) z += __shfl_xor(z, m, 64);
        if (lane == 0) zsh[0] = z;
    } else if (wv == 1) {  // ZS: 128 entries
        float z = ws[ZS_OFF + lane] + ws[ZS_OFF + 64 + lane];
        #pragma unroll
        for (int m = 32; m >= 1; m >>= 1) z += __shfl_xor(z, m, 64);
        if (lane == 0) zsh[1] = z;
    }
    __syncthreads();
    const float invZp = 1.f / zsh[0];
    const float invZs = 1.f / zsh[1];

    const bool needP = start4 < (O1 / 4);
    const bool needS = (end4 > (O2 / 4)) && (start4 < (O3 / 4));

    if (needP) {   // u_p = BPC + invZs * sum over 128 RS partials (DP each)
        {
            const int c = t & 255, g = t >> 8;     // 2 groups of 64 blocks
            float a = 0.f;
            #pragma unroll 8
            for (int b2 = g * 64; b2 < g * 64 + 64; ++b2) a += ws[RS_OFF + b2 * DP + c];
            red[t] = a;
        }
        __syncthreads();
        if (t < DP) up[t] = ws[BPC + t] + invZs * (red[t] + red[t + 256]);
        __syncthreads();
    }
    if (needS) {   // u_s = BSC + invZp * sum over 256 RP partials (DS each)
        {
            const int c = t & 127, g = t >> 7;     // 4 groups of 64 blocks
            float a = 0.f;
            #pragma unroll 8
            for (int b1 = g * 64; b1 < g * 64 + 64; ++b1) a += ws[RP_OFF + b1 * DS + c];
            red[t] = a;
        }
        __syncthreads();
        if (t < DS) us[t] = ws[BSC + t] + invZp * (red[t] + red[t + 128] + red[t + 256] + red[t + 384]);
        __syncthreads();
    }

    for (int g4 = start4 + t; g4 < end4; g4 += 512) {
        const int e4 = g4 * 4;
        float4 o;
        if (e4 < O1) {
            float4 x = *(const float4*)(pn + e4);
            int c = e4 & (DP - 1);
            o = make_float4(x.x + up[c], x.y + up[c + 1], x.z + up[c + 2], x.w + up[c + 3]);
        } else if (e4 < O2) {
            int i = e4 - O1;
            int4 v = *(const int4*)(pidx + i);
            o = make_float4((float)v.x, (float)v.y, (float)v.z, (float)v.w);
        } else if (e4 < O3) {
            int i = e4 - O2;
            float4 x = *(const float4*)(sn + i);
            int c = i & (DS - 1);
            o = make_float4(x.x + us[c], x.y + us[c + 1], x.z + us[c + 2], x.w + us[c + 3]);
        } else {
            int i = e4 - O3;
            int4 v = *(const int4*)(sidx + i);
            o = make_float4((float)v.x, (float)v.y, (float)v.z, (float)v.w);
        }
        *(float4*)(out + e4) = o;
    }
}

extern "C" void kernel_launch(void* const* d_in, const int* in_sizes, int n_in,
                              void* d_out, int out_size, void* d_ws, size_t ws_size,
                              hipStream_t stream) {
    const float* pn  = (const float*)d_in[0];
    const float* sn  = (const float*)d_in[1];
    const float* Wpp = (const float*)d_in[2];
    const float* bpp = (const float*)d_in[3];
    const float* Wsp = (const float*)d_in[4];
    const float* bsp = (const float*)d_in[5];
    const float* Wpo = (const float*)d_in[6];
    const float* bpo = (const float*)d_in[7];
    const float* Wso = (const float*)d_in[8];
    const float* bso = (const float*)d_in[9];
    const int* pidx  = (const int*)d_in[10];
    const int* sidx  = (const int*)d_in[11];
    float* ws  = (float*)d_ws;
    float* out = (float*)d_out;

    hipLaunchKernelGGL(k1, dim3(G1), dim3(BLK1), 0, stream,
                       pn, sn, Wpp, bpp, Wsp, bsp, Wpo, bpo, Wso, bso, pidx, sidx, ws);
    hipLaunchKernelGGL(k2, dim3(G2), dim3(512), 0, stream,
                       pn, sn, pidx, sidx, ws, out);
}

// Round 11
// 29.960 us; speedup vs baseline: 1.3620x; 1.3620x over previous
//
#include <hip/hip_runtime.h>

#define NP 16384
#define NS 8192
#define DP 256
#define DS 128
#define DI 128

#define NBP 128   // k1 prot blocks (128 rows each)
#define NBS 64    // k1 sub blocks (128 rows each)

// ---- ws float offsets ----
#define RP_OFF 0                     // [NBP][DS]  projected prot partials (-> u_s)
#define RS_OFF (RP_OFF + NBP*DS)     // [NBS][DP]  projected sub partials (-> u_p)
#define ZP_OFF (RS_OFF + NBS*DP)     // [NBP]
#define ZS_OFF (ZP_OFF + NBP)        // [NBS]
#define BSC    (ZS_OFF + NBS)        // [DS]  bso + Wso^T bpp
#define BPC    (BSC + DS)            // [DP]  bpo + Wpo^T bsp

// ---- out float4 offsets ----
#define O1 (NP*DP)
#define O2 (O1 + NP)
#define O3 (O2 + NS*DS)
#define TOTAL (O3 + NS)
#define TOTAL4 (TOTAL/4)
#define GK2 1024
#define CHUNK (TOTAL4/GK2)   // 1286 exactly

__device__ __forceinline__ float wsum64(float s) {
    #pragma unroll
    for (int m = 32; m >= 1; m >>= 1) s += __shfl_xor(s, m, 64);
    return s;
}

// ---- k1: fused gather-weight + weighted colsum + per-block projection ----
__global__ __launch_bounds__(512)
void k1(const float* __restrict__ pn, const float* __restrict__ sn,
        const float* __restrict__ Wpp, const float* __restrict__ bpp,
        const float* __restrict__ Wsp, const float* __restrict__ bsp,
        const float* __restrict__ Wpo, const float* __restrict__ bpo,
        const float* __restrict__ Wso, const float* __restrict__ bso,
        const int* __restrict__ pidx, const int* __restrict__ sidx,
        float* __restrict__ ws) {
    __shared__ float wcol[DP];
    __shared__ float racc[8 * DP];
    __shared__ float rz[8];
    __shared__ float acc2[DP];
    __shared__ float qv[DI];
    __shared__ float red[512];
    const int t = threadIdx.x;
    const int lane = t & 63;
    const int wv = t >> 6;
    const int b = blockIdx.x;

    if (b < NBP) {
        // ---- prot side: weights exp(dot(pn[pidx[i]], wsum_p)), values pn[i] ----
        if (t < DP) {
            const float4* row = (const float4*)(Wpp + t * DI);
            float s = 0.f;
            #pragma unroll
            for (int d = 0; d < DI / 4; ++d) { float4 v = row[d]; s += v.x + v.y + v.z + v.w; }
            wcol[t] = s;
        }
        __syncthreads();
        const float4 wp = *(const float4*)(wcol + lane * 4);
        float4 acc = make_float4(0.f, 0.f, 0.f, 0.f);
        float z = 0.f;
        const int base = (b * 8 + wv) * 16;
        #pragma unroll
        for (int k = 0; k < 16; k += 2) {
            const int i0 = base + k, i1 = base + k + 1;
            const int g0 = pidx[i0], g1 = pidx[i1];
            const float4 x0 = *(const float4*)(pn + (size_t)g0 * DP + lane * 4);
            const float4 x1 = *(const float4*)(pn + (size_t)g1 * DP + lane * 4);
            float s0 = x0.x * wp.x + x0.y * wp.y + x0.z * wp.z + x0.w * wp.w;
            float s1 = x1.x * wp.x + x1.y * wp.y + x1.z * wp.z + x1.w * wp.w;
            #pragma unroll
            for (int m = 32; m >= 1; m >>= 1) {
                s0 += __shfl_xor(s0, m, 64);
                s1 += __shfl_xor(s1, m, 64);
            }
            const float e0 = __expf(s0), e1 = __expf(s1);
            const float4 y0 = *(const float4*)(pn + (size_t)i0 * DP + lane * 4);
            const float4 y1 = *(const float4*)(pn + (size_t)i1 * DP + lane * 4);
            acc.x += e0 * y0.x + e1 * y1.x;
            acc.y += e0 * y0.y + e1 * y1.y;
            acc.z += e0 * y0.z + e1 * y1.z;
            acc.w += e0 * y0.w + e1 * y1.w;
            z += e0 + e1;
        }
        ((float4*)(racc + wv * DP))[lane] = acc;
        if (lane == 0) rz[wv] = z;
        __syncthreads();
        if (t < DP) {
            float s = 0.f;
            #pragma unroll
            for (int w = 0; w < 8; ++w) s += racc[w * DP + t];
            acc2[t] = s;
        }
        if (t == 0) {
            float s = 0.f;
            #pragma unroll
            for (int w = 0; w < 8; ++w) s += rz[w];
            ws[ZP_OFF + b] = s;
        }
        __syncthreads();
        // stage A: q[d] = sum_c acc2[c]*Wpp[c][d]
        {
            const int d = t & 127, g = t >> 7;
            float a = 0.f;
            #pragma unroll 8
            for (int c = g * 64; c < g * 64 + 64; ++c) a += acc2[c] * Wpp[c * DI + d];
            red[t] = a;
        }
        __syncthreads();
        if (t < DI) qv[t] = red[t] + red[t + 128] + red[t + 256] + red[t + 384];
        __syncthreads();
        // stage B: r[c] = sum_d qv[d]*Wso[d][c]
        {
            const int c = t & 127, g = t >> 7;
            float a = 0.f;
            #pragma unroll 8
            for (int d = g * 32; d < g * 32 + 32; ++d) a += qv[d] * Wso[d * DS + c];
            red[t] = a;
        }
        __syncthreads();
        if (t < DS) ws[RP_OFF + b * DS + t] = red[t] + red[t + 128] + red[t + 256] + red[t + 384];
        if (b == 0) {   // BS_const = bso + Wso^T bpp
            __syncthreads();
            {
                const int c = t & 127, g = t >> 7;
                float a = 0.f;
                #pragma unroll 8
                for (int d = g * 32; d < g * 32 + 32; ++d) a += bpp[d] * Wso[d * DS + c];
                red[t] = a;
            }
            __syncthreads();
            if (t < DS) ws[BSC + t] = bso[t] + red[t] + red[t + 128] + red[t + 256] + red[t + 384];
        }
    } else {
        // ---- sub side ----
        const int b2 = b - NBP;
        if (t < DS) {
            const float4* row = (const float4*)(Wsp + t * DI);
            float s = 0.f;
            #pragma unroll
            for (int d = 0; d < DI / 4; ++d) { float4 v = row[d]; s += v.x + v.y + v.z + v.w; }
            wcol[t] = s;
        }
        __syncthreads();
        const float2 wp = *(const float2*)(wcol + lane * 2);
        float2 acc = make_float2(0.f, 0.f);
        float z = 0.f;
        const int base = (b2 * 8 + wv) * 16;
        #pragma unroll
        for (int k = 0; k < 16; k += 2) {
            const int j0 = base + k, j1 = base + k + 1;
            const int g0 = sidx[j0], g1 = sidx[j1];
            const float2 x0 = *(const float2*)(sn + (size_t)g0 * DS + lane * 2);
            const float2 x1 = *(const float2*)(sn + (size_t)g1 * DS + lane * 2);
            float s0 = x0.x * wp.x + x0.y * wp.y;
            float s1 = x1.x * wp.x + x1.y * wp.y;
            #pragma unroll
            for (int m = 32; m >= 1; m >>= 1) {
                s0 += __shfl_xor(s0, m, 64);
                s1 += __shfl_xor(s1, m, 64);
            }
            const float e0 = __expf(s0), e1 = __expf(s1);
            const float2 y0 = *(const float2*)(sn + (size_t)j0 * DS + lane * 2);
            const float2 y1 = *(const float2*)(sn + (size_t)j1 * DS + lane * 2);
            acc.x += e0 * y0.x + e1 * y1.x;
            acc.y += e0 * y0.y + e1 * y1.y;
            z += e0 + e1;
        }
        ((float2*)(racc + wv * DS))[lane] = acc;
        if (lane == 0) rz[wv] = z;
        __syncthreads();
        if (t < DS) {
            float s = 0.f;
            #pragma unroll
            for (int w = 0; w < 8; ++w) s += racc[w * DS + t];
            acc2[t] = s;
        }
        if (t == 0) {
            float s = 0.f;
            #pragma unroll
            for (int w = 0; w < 8; ++w) s += rz[w];
            ws[ZS_OFF + b2] = s;
        }
        __syncthreads();
        // stage A: q[d] = sum_c acc2[c]*Wsp[c][d]
        {
            const int d = t & 127, g = t >> 7;
            float a = 0.f;
            #pragma unroll 8
            for (int c = g * 32; c < g * 32 + 32; ++c) a += acc2[c] * Wsp[c * DI + d];
            red[t] = a;
        }
        __syncthreads();
        if (t < DI) qv[t] = red[t] + red[t + 128] + red[t + 256] + red[t + 384];
        __syncthreads();
        // stage B: r[c] = sum_d qv[d]*Wpo[d][c], c < 256
        {
            const int c = t & 255, g = t >> 8;
            float a = 0.f;
            #pragma unroll 8
            for (int d = g * 64; d < g * 64 + 64; ++d) a += qv[d] * Wpo[d * DP + c];
            red[t] = a;
        }
        __syncthreads();
        if (t < DP) ws[RS_OFF + b2 * DP + t] = red[t] + red[t + 256];
        if (b2 == 0) {  // BP_const = bpo + Wpo^T bsp
            __syncthreads();
            {
                const int c = t & 255, g = t >> 8;
                float a = 0.f;
                #pragma unroll 8
                for (int d = g * 64; d < g * 64 + 64; ++d) a += bsp[d] * Wpo[d * DP + c];
                red[t] = a;
            }
            __syncthreads();
            if (t < DP) ws[BPC + t] = bpo[t] + red[t] + red[t + 256];
        }
    }
}

// ---- k2: per-block redundant combine (only the side needed) + finalize ----
__global__ __launch_bounds__(512)
void k2(const float* __restrict__ pn, const float* __restrict__ sn,
        const int* __restrict__ pidx, const int* __restrict__ sidx,
        const float* __restrict__ ws, float* __restrict__ out) {
    __shared__ float up[DP];
    __shared__ float us[DS];
    __shared__ float red[512];
    __shared__ float zsh[2];
    const int t = threadIdx.x;
    const int lane = t & 63;
    const int wv = t >> 6;
    const int b = blockIdx.x;
    const int start4 = b * CHUNK;
    const int end4 = start4 + CHUNK;

    if (wv == 0) {
        float z = ws[ZP_OFF + lane] + ws[ZP_OFF + 64 + lane];
        z = wsum64(z);
        if (lane == 0) zsh[0] = z;
    } else if (wv == 1) {
        float z = ws[ZS_OFF + lane];
        z = wsum64(z);
        if (lane == 0) zsh[1] = z;
    }
    __syncthreads();
    const float invZp = 1.f / zsh[0];
    const float invZs = 1.f / zsh[1];

    const bool needP = start4 < (O1 / 4);
    const bool needS = (end4 > (O2 / 4)) && (start4 < (O3 / 4));

    if (needP) {   // u_p from sub-side projected partials
        {
            const int c = t & 255, g = t >> 8;
            float a = 0.f;
            #pragma unroll 8
            for (int b2 = g * 32; b2 < g * 32 + 32; ++b2) a += ws[RS_OFF + b2 * DP + c];
            red[t] = a;
        }
        __syncthreads();
        if (t < DP) up[t] = ws[BPC + t] + invZs * (red[t] + red[t + 256]);
        __syncthreads();
    }
    if (needS) {   // u_s from prot-side projected partials
        {
            const int c = t & 127, g = t >> 7;
            float a = 0.f;
            #pragma unroll 8
            for (int b1 = g * 32; b1 < g * 32 + 32; ++b1) a += ws[RP_OFF + b1 * DS + c];
            red[t] = a;
        }
        __syncthreads();
        if (t < DS) us[t] = ws[BSC + t] + invZp * (red[t] + red[t + 128] + red[t + 256] + red[t + 384]);
        __syncthreads();
    }

    for (int g4 = start4 + t; g4 < end4; g4 += 512) {
        const int e4 = g4 * 4;
        float4 o;
        if (e4 < O1) {
            float4 x = *(const float4*)(pn + e4);
            int c = e4 & (DP - 1);
            o = make_float4(x.x + up[c], x.y + up[c + 1], x.z + up[c + 2], x.w + up[c + 3]);
        } else if (e4 < O2) {
            int i = e4 - O1;
            int4 v = *(const int4*)(pidx + i);
            o = make_float4((float)v.x, (float)v.y, (float)v.z, (float)v.w);
        } else if (e4 < O3) {
            int i = e4 - O2;
            float4 x = *(const float4*)(sn + i);
            int c = i & (DS - 1);
            o = make_float4(x.x + us[c], x.y + us[c + 1], x.z + us[c + 2], x.w + us[c + 3]);
        } else {
            int i = e4 - O3;
            int4 v = *(const int4*)(sidx + i);
            o = make_float4((float)v.x, (float)v.y, (float)v.z, (float)v.w);
        }
        *(float4*)(out + e4) = o;
    }
}

extern "C" void kernel_launch(void* const* d_in, const int* in_sizes, int n_in,
                              void* d_out, int out_size, void* d_ws, size_t ws_size,
                              hipStream_t stream) {
    const float* pn  = (const float*)d_in[0];
    const float* sn  = (const float*)d_in[1];
    const float* Wpp = (const float*)d_in[2];
    const float* bpp = (const float*)d_in[3];
    const float* Wsp = (const float*)d_in[4];
    const float* bsp = (const float*)d_in[5];
    const float* Wpo = (const float*)d_in[6];
    const float* bpo = (const float*)d_in[7];
    const float* Wso = (const float*)d_in[8];
    const float* bso = (const float*)d_in[9];
    const int* pidx  = (const int*)d_in[10];
    const int* sidx  = (const int*)d_in[11];
    float* ws  = (float*)d_ws;
    float* out = (float*)d_out;

    hipLaunchKernelGGL(k1, dim3(NBP + NBS), dim3(512), 0, stream,
                       pn, sn, Wpp, bpp, Wsp, bsp, Wpo, bpo, Wso, bso, pidx, sidx, ws);
    hipLaunchKernelGGL(k2, dim3(GK2), dim3(512), 0, stream,
                       pn, sn, pidx, sidx, ws, out);
}